// Round 3
// baseline (605.876 us; speedup 1.0000x reference)
//
#include <hip/hip_runtime.h>
#include <stdint.h>
#include <stddef.h>

// DKVMN: B=64,T=100, DK=DV=N=128, NUM_Q=1000.
// Device dtypes: float32 in, float32 out (bisection: bf16 input-read -> NaN,
// bf16 output-write -> 0.87 error with the exact aliasing signature of bf16
// pairs in an f32 buffer). Comparison threshold is bf16-precision (2%).
// Decomposition:
//   kernel A: w/e/a/ftk are state-independent -> precompute for all (b,t).
//   kernel B: Mv recurrence elementwise per (b,n,d) -> 1M parallel chains,
//             f32 state in registers, float4 stores.
//   kernel C: p recomputed from the materialized Mv (all (b,t) parallel).

constexpr int B = 64;
constexpr int T = 100;
constexpr int D = 128;        // DK = DV = N
constexpr int NUM_Q = 1000;
constexpr int G = 4;          // timesteps per block in kernel A
constexpr int BT = B * T;     // 6400
constexpr int WSTRIDE = BT * D; // 819200 floats per ws plane

__device__ __forceinline__ float sigmoidf_(float x) {
  return 1.0f / (1.0f + __expf(-x));
}

// ---------------- Kernel A: per-(b,t) precompute w, e, a, ftk ----------------
__global__ __launch_bounds__(128) void kernelA(
    const int* __restrict__ q, const int* __restrict__ r,
    const float* __restrict__ k_emb, const float* __restrict__ v_emb,
    const float* __restrict__ Mk,
    const float* __restrict__ f_W, const float* __restrict__ f_b,
    const float* __restrict__ e_W, const float* __restrict__ e_b,
    const float* __restrict__ a_W, const float* __restrict__ a_b,
    float* __restrict__ ws_w, float* __restrict__ ws_e,
    float* __restrict__ ws_a, float* __restrict__ ws_f)
{
  const int tid = threadIdx.x;
  const int b  = blockIdx.x / (T / G);
  const int tg = blockIdx.x % (T / G);
  const int tbase = tg * G;

  __shared__ float kt[G][D];
  __shared__ float vt[G][D];
  __shared__ float red[D];

  #pragma unroll
  for (int g = 0; g < G; ++g) {
    int idx = b * T + tbase + g;
    int qi  = q[idx];
    int qri = qi + NUM_Q * r[idx];
    kt[g][tid] = k_emb[qi * D + tid];
    vt[g][tid] = v_emb[qri * D + tid];
  }
  __syncthreads();

  float lg[G], se[G], sa[G], sf[G];
  #pragma unroll
  for (int g = 0; g < G; ++g) { lg[g] = 0.f; se[g] = 0.f; sa[g] = 0.f; sf[g] = 0.f; }

  #pragma unroll 4
  for (int k = 0; k < D; ++k) {
    float mk = Mk[k * D + tid];
    float ew = e_W[k * D + tid];
    float aw = a_W[k * D + tid];
    float fw = f_W[(D + k) * D + tid];   // kt-half of f_W (rows 128..255)
    #pragma unroll
    for (int g = 0; g < G; ++g) {
      float kk = kt[g][k];
      float vv = vt[g][k];
      lg[g] = fmaf(kk, mk, lg[g]);
      se[g] = fmaf(vv, ew, se[g]);
      sa[g] = fmaf(vv, aw, sa[g]);
      sf[g] = fmaf(kk, fw, sf[g]);
    }
  }

  const float eb = e_b[tid];
  const float ab = a_b[tid];
  const float fb = f_b[tid];

  for (int g = 0; g < G; ++g) {
    // softmax over the 128 logits (one per thread)
    red[tid] = lg[g];
    __syncthreads();
    #pragma unroll
    for (int s = 64; s > 0; s >>= 1) {
      if (tid < s) red[tid] = fmaxf(red[tid], red[tid + s]);
      __syncthreads();
    }
    float mx = red[0];
    __syncthreads();
    float ex = __expf(lg[g] - mx);
    red[tid] = ex;
    __syncthreads();
    #pragma unroll
    for (int s = 64; s > 0; s >>= 1) {
      if (tid < s) red[tid] += red[tid + s];
      __syncthreads();
    }
    float sm = red[0];
    __syncthreads();

    int idx = (b * T + tbase + g) * D + tid;
    ws_w[idx] = ex / sm;
    ws_e[idx] = sigmoidf_(se[g] + eb);
    ws_a[idx] = tanhf(sa[g] + ab);
    ws_f[idx] = sf[g] + fb;
  }
}

// ---------------- Kernel B: Mv scan, f32 state in registers ----------------
// block: 256 threads = 16 n-rows x 16 d-groups(8 floats each); grid: B x 8 n-tiles
__global__ __launch_bounds__(256) void kernelB(
    const float* __restrict__ Mv0,
    const float* __restrict__ ws_w, const float* __restrict__ ws_e,
    const float* __restrict__ ws_a,
    float* __restrict__ out_Mv)
{
  const int b  = blockIdx.x >> 3;
  const int nt = blockIdx.x & 7;
  const int tid = threadIdx.x;
  const int nrow = tid >> 4;
  const int dgrp = tid & 15;
  const int n  = nt * 16 + nrow;
  const int d0 = dgrp * 8;

  float m[8];
  #pragma unroll
  for (int i = 0; i < 8; ++i) m[i] = Mv0[n * D + d0 + i];

  for (int t = 0; t < T; ++t) {
    const int base = (b * T + t) * D;
    float wv = ws_w[base + n];
    const float4* ep = (const float4*)(ws_e + base + d0);
    const float4* ap = (const float4*)(ws_a + base + d0);
    float4 e0 = ep[0], e1 = ep[1];
    float4 a0 = ap[0], a1 = ap[1];
    float ee[8] = {e0.x, e0.y, e0.z, e0.w, e1.x, e1.y, e1.z, e1.w};
    float aa[8] = {a0.x, a0.y, a0.z, a0.w, a1.x, a1.y, a1.z, a1.w};
    #pragma unroll
    for (int i = 0; i < 8; ++i) {
      m[i] = m[i] * (1.0f - wv * ee[i]) + wv * aa[i];
    }
    size_t obase = ((size_t)(t * B + b) * D + n) * D + d0;
    float4 o0 = make_float4(m[0], m[1], m[2], m[3]);
    float4 o1 = make_float4(m[4], m[5], m[6], m[7]);
    *(float4*)(out_Mv + obase)     = o0;  // obase mult of 8 floats; out_Mv off 25600 B
    *(float4*)(out_Mv + obase + 4) = o1;
  }
}

// ---------------- Kernel C: p from materialized Mv ----------------
__global__ __launch_bounds__(128) void kernelC(
    const float* __restrict__ Mv0,
    const float* __restrict__ f_W,
    const float* __restrict__ p_W,
    const float* __restrict__ p_b,
    const float* __restrict__ ws_w, const float* __restrict__ ws_f,
    const float* __restrict__ out_Mv,
    float* __restrict__ out_p)
{
  const int bt = blockIdx.x;
  const int b = bt / T;
  const int t = bt % T;
  const int tid = threadIdx.x;

  __shared__ float wsh[D];
  __shared__ float rsh[D];
  __shared__ float red[D];

  const int base = (b * T + t) * D;
  wsh[tid] = ws_w[base + tid];
  __syncthreads();

  // state entering step t = Mv output of step t-1 (Mv0 for t==0)
  const float* Mp = (t == 0)
      ? Mv0
      : (out_Mv + (size_t)((t - 1) * B + b) * (D * D));

  float rt = 0.f;
  #pragma unroll 8
  for (int n = 0; n < D; ++n) rt = fmaf(wsh[n], Mp[n * D + tid], rt);
  rsh[tid] = rt;
  __syncthreads();

  float fa = ws_f[base + tid];   // ftk = kt-half @ f_W + f_b, precomputed
  #pragma unroll 8
  for (int d2 = 0; d2 < D; ++d2) fa = fmaf(rsh[d2], f_W[d2 * D + tid], fa);
  float ft = tanhf(fa);

  red[tid] = ft * p_W[tid];
  __syncthreads();
  #pragma unroll
  for (int s = 64; s > 0; s >>= 1) {
    if (tid < s) red[tid] += red[tid + s];
    __syncthreads();
  }
  if (tid == 0) {
    float pt = sigmoidf_(red[0] + p_b[0]);
    out_p[t * B + b] = pt;
  }
}

extern "C" void kernel_launch(void* const* d_in, const int* in_sizes, int n_in,
                              void* d_out, int out_size, void* d_ws, size_t ws_size,
                              hipStream_t stream)
{
  const int* q = (const int*)d_in[0];
  const int* r = (const int*)d_in[1];
  const float* k_emb = (const float*)d_in[2];
  const float* v_emb = (const float*)d_in[3];
  const float* Mk   = (const float*)d_in[4];
  const float* Mv0  = (const float*)d_in[5];
  const float* f_W  = (const float*)d_in[6];
  const float* f_b  = (const float*)d_in[7];
  const float* p_W  = (const float*)d_in[8];
  const float* p_b  = (const float*)d_in[9];
  const float* e_W  = (const float*)d_in[10];
  const float* e_b  = (const float*)d_in[11];
  const float* a_W  = (const float*)d_in[12];
  const float* a_b  = (const float*)d_in[13];

  float* ws   = (float*)d_ws;   // 4 planes x 819200 f32 = 13.1 MB
  float* ws_w = ws;
  float* ws_e = ws + (size_t)WSTRIDE;
  float* ws_a = ws + (size_t)2 * WSTRIDE;
  float* ws_f = ws + (size_t)3 * WSTRIDE;

  float* out    = (float*)d_out;
  float* out_p  = out;            // p: first BT elements, layout (T*B,1)
  float* out_Mv = out + BT;       // Mv: (T*B,128,128)

  hipLaunchKernelGGL(kernelA, dim3(B * (T / G)), dim3(D), 0, stream,
                     q, r, k_emb, v_emb, Mk, f_W, f_b, e_W, e_b, a_W, a_b,
                     ws_w, ws_e, ws_a, ws_f);
  hipLaunchKernelGGL(kernelB, dim3(B * 8), dim3(256), 0, stream,
                     Mv0, ws_w, ws_e, ws_a, out_Mv);
  hipLaunchKernelGGL(kernelC, dim3(BT), dim3(D), 0, stream,
                     Mv0, f_W, p_W, p_b, ws_w, ws_f, out_Mv, out_p);
}